// Round 2
// baseline (769.928 us; speedup 1.0000x reference)
//
#include <hip/hip_runtime.h>
#include <hip/hip_bf16.h>
#include <math.h>

#define D_MODEL 512
#define D_FF    2048
#define NE      8
#define T_TOK   8192
#define BM      64
#define FSPLIT  2
#define FH      (D_FF / FSPLIT)   // 1024 f per block
#define NFC     (FH / 64)         // 16 chunks of 64

typedef __attribute__((ext_vector_type(8))) short bf16x8;
typedef __attribute__((ext_vector_type(4))) float f32x4;

static __device__ __forceinline__ unsigned short f2bf(float f){
    union { float f; unsigned u; } v; v.f = f;
    unsigned r = v.u + 0x7FFFu + ((v.u >> 16) & 1u);   // RNE
    return (unsigned short)(r >> 16);
}

// ---------------- f32 -> bf16 conversion (weights) ----------------
__global__ __launch_bounds__(256) void cvt_f32_bf16(const float* __restrict__ src,
                                                    unsigned short* __restrict__ dst,
                                                    int n4){
    int i = blockIdx.x * blockDim.x + threadIdx.x;
    int stride = gridDim.x * blockDim.x;
    for (; i < n4; i += stride){
        float4 v = ((const float4*)src)[i];
        ushort4 o;
        o.x = f2bf(v.x); o.y = f2bf(v.y); o.z = f2bf(v.z); o.w = f2bf(v.w);
        ((ushort4*)dst)[i] = o;
    }
}

// ------------- router (fused with x->bf16): logits -> softmax -> top2 -> scatter -------------
__global__ __launch_bounds__(256) void router_kernel(const float* __restrict__ x,
                                                     const float* __restrict__ Wr,
                                                     unsigned short* __restrict__ x_bf,
                                                     float* __restrict__ pair_prob,
                                                     int* __restrict__ lists,
                                                     int* __restrict__ cnt){
    int gid  = blockIdx.x * blockDim.x + threadIdx.x;
    int t    = gid >> 6;              // one wave per token
    int lane = threadIdx.x & 63;
    if (t >= T_TOK) return;
    const float* xr = x + (size_t)t * D_MODEL;
    float xv[8];
    #pragma unroll
    for (int c = 0; c < 8; ++c) xv[c] = xr[lane + 64*c];
    // emit bf16 copy of x
    unsigned short* xb = x_bf + (size_t)t * D_MODEL;
    #pragma unroll
    for (int c = 0; c < 8; ++c) xb[lane + 64*c] = f2bf(xv[c]);
    float lg[NE];
    #pragma unroll
    for (int e = 0; e < NE; ++e){
        const float* wr = Wr + (size_t)e * D_MODEL;
        float s = 0.f;
        #pragma unroll
        for (int c = 0; c < 8; ++c) s = fmaf(xv[c], wr[lane + 64*c], s);
        #pragma unroll
        for (int off = 32; off; off >>= 1) s += __shfl_xor(s, off);
        lg[e] = s;
    }
    if (lane == 0){
        float m = lg[0];
        #pragma unroll
        for (int e = 1; e < NE; ++e) m = fmaxf(m, lg[e]);
        float sum = 0.f;
        #pragma unroll
        for (int e = 0; e < NE; ++e) sum += expf(lg[e] - m);
        int i0 = 0; float v0 = lg[0];
        #pragma unroll
        for (int e = 1; e < NE; ++e) if (lg[e] > v0){ v0 = lg[e]; i0 = e; }
        int i1 = -1; float v1 = -1e30f;
        #pragma unroll
        for (int e = 0; e < NE; ++e) if (e != i0 && lg[e] > v1){ v1 = lg[e]; i1 = e; }
        float inv = 1.f / sum;
        pair_prob[2*t]   = expf(v0 - m) * inv;
        pair_prob[2*t+1] = expf(v1 - m) * inv;
        int pos0 = atomicAdd(&cnt[i0], 1);
        lists[i0 * T_TOK + pos0] = 2*t;
        int pos1 = atomicAdd(&cnt[i1], 1);
        lists[i1 * T_TOK + pos1] = 2*t + 1;
    }
}

// ---------------- fused expert FFN ----------------
// 512 thr (8 waves: tok-half x quarter), tile = 64 pairs of one expert, f-range = 1024 per block
// LDS: x 64KB + h dbuf 16KB = 80KB -> 2 blocks/CU
__global__ __launch_bounds__(512, 4) void moe_ffn_kernel(const unsigned short* __restrict__ x_bf,
                                                         const unsigned short* __restrict__ W1bf,
                                                         const unsigned short* __restrict__ W2bf,
                                                         const float* __restrict__ pair_prob,
                                                         const int* __restrict__ lists,
                                                         const int* __restrict__ cnt,
                                                         float* __restrict__ out0,
                                                         float* __restrict__ out1){
    __shared__ __align__(16) unsigned char lds_x[BM * 1024];      // 64 rows x 512 bf16, swizzled
    __shared__ __align__(16) unsigned char lds_h[2][BM * 128];    // dbuf: 64 rows x 64 bf16, swizzled

    // XCD-grouped decode: xcd (bid&7) owns experts {e, e+4} at f-half (bid&1 of xcd id)
    int bid  = blockIdx.x;
    int xcd  = bid & 7, slot = bid >> 3;
    int eA   = xcd >> 1, sA = xcd & 1;
    int eB   = eA + 4;
    int tA   = (cnt[eA] + BM - 1) >> 6;
    int tB   = (cnt[eB] + BM - 1) >> 6;
    int e, sp, tile;
    if (slot < tA)           { e = eA; sp = sA; tile = slot; }
    else if (slot < tA + tB) { e = eB; sp = sA; tile = slot - tA; }
    else return;
    int ne = cnt[e];

    int tid = threadIdx.x;
    // ---- stage gathered X rows (bf16) into swizzled LDS
    {
        int row = tid >> 3;
        int idx = tile * BM + row;
        int tok = 0;
        if (idx < ne) tok = lists[e * T_TOK + idx] >> 1;
        int seg = (tid & 7) * 64;
        const unsigned short* src = x_bf + (size_t)tok * D_MODEL + seg;
        int sw = (row & 7) << 4;
        #pragma unroll
        for (int g = 0; g < 8; ++g){
            int4 v = *(const int4*)(src + g * 8);
            int col2 = (seg + g * 8) * 2;
            *(int4*)(lds_x + row * 1024 + (col2 ^ sw)) = v;
        }
    }
    __syncthreads();

    int wv = tid >> 6, lane = tid & 63, l15 = lane & 15, lk = lane >> 4;
    int th = wv & 1;          // token half (32 rows)
    int q  = wv >> 1;         // f-quarter (GEMM1) / d-quarter (GEMM2)
    int ar0 = th * 32 + l15, ar1 = ar0 + 16;
    int swz = (l15 & 7) << 4;

    f32x4 zero4 = {0.f, 0.f, 0.f, 0.f};
    f32x4 yacc[2][8];
    #pragma unroll
    for (int i = 0; i < 2; ++i)
        #pragma unroll
        for (int j = 0; j < 8; ++j) yacc[i][j] = zero4;

    const unsigned short* w1p0 = W1bf + ((size_t)e * D_FF + sp * FH + q * 16 + l15) * D_MODEL + lk * 8;
    const unsigned short* w2p0 = W2bf + ((size_t)e * D_MODEL + q * 128 + l15) * D_FF + sp * FH + lk * 8;

    #pragma unroll 2
    for (int fc = 0; fc < NFC; ++fc){
        // ---- GEMM1: H[64][64] slab, K=512; this wave computes 32 tok x 16 f
        f32x4 hacc0 = zero4, hacc1 = zero4;
        const unsigned short* w1p = w1p0 + (size_t)(fc * 64) * D_MODEL;
        #pragma unroll
        for (int ks = 0; ks < 16; ++ks){
            int col2 = (ks * 32 + lk * 8) * 2;
            bf16x8 a0 = *(const bf16x8*)(lds_x + ar0 * 1024 + (col2 ^ swz));
            bf16x8 a1 = *(const bf16x8*)(lds_x + ar1 * 1024 + (col2 ^ swz));
            bf16x8 bb = *(const bf16x8*)(w1p + ks * 32);
            hacc0 = __builtin_amdgcn_mfma_f32_16x16x32_bf16(a0, bb, hacc0, 0, 0, 0);
            hacc1 = __builtin_amdgcn_mfma_f32_16x16x32_bf16(a1, bb, hacc1, 0, 0, 0);
        }
        // ---- GELU (exact erf) -> bf16 h[cur] (other waves read h[cur^1] until their barrier: safe)
        unsigned char* hb = lds_h[fc & 1];
        {
            int fl2 = (q * 16 + l15) * 2;
            #pragma unroll
            for (int r = 0; r < 4; ++r){
                int t0r = th * 32 + lk * 4 + r;
                float g0 = hacc0[r];
                g0 = 0.5f * g0 * (1.f + erff(g0 * 0.70710678118654752f));
                *(unsigned short*)(hb + t0r * 128 + (fl2 ^ ((t0r & 7) << 4))) = f2bf(g0);
                int t1r = t0r + 16;
                float g1 = hacc1[r];
                g1 = 0.5f * g1 * (1.f + erff(g1 * 0.70710678118654752f));
                *(unsigned short*)(hb + t1r * 128 + (fl2 ^ ((t1r & 7) << 4))) = f2bf(g1);
            }
        }
        // barrier WITHOUT vmcnt drain: only LDS ops must settle; global loads stay in flight
        asm volatile("s_waitcnt lgkmcnt(0)\n\ts_barrier" ::: "memory");
        // ---- GEMM2: Y[64][512] += H(64x64) * W2[:, chunk]^T; this wave: 32 tok x 128 d
        const unsigned short* w2p = w2p0 + fc * 64;
        #pragma unroll
        for (int ks2 = 0; ks2 < 2; ++ks2){
            int col2 = (ks2 * 32 + lk * 8) * 2;
            bf16x8 a0 = *(const bf16x8*)(hb + ar0 * 128 + (col2 ^ swz));
            bf16x8 a1 = *(const bf16x8*)(hb + ar1 * 128 + (col2 ^ swz));
            #pragma unroll
            for (int nt = 0; nt < 8; ++nt){
                bf16x8 bb = *(const bf16x8*)(w2p + (size_t)nt * 16 * D_FF + ks2 * 32);
                yacc[0][nt] = __builtin_amdgcn_mfma_f32_16x16x32_bf16(a0, bb, yacc[0][nt], 0, 0, 0);
                yacc[1][nt] = __builtin_amdgcn_mfma_f32_16x16x32_bf16(a1, bb, yacc[1][nt], 0, 0, 0);
            }
        }
    }

    // ---- epilogue: dst[tok] += p * Y  (2 commutative atomics per element per dst -> deterministic)
    float* dst = (sp == 0) ? out0 : out1;
    const int* lrow = lists + e * T_TOK + tile * BM;
    #pragma unroll
    for (int mt = 0; mt < 2; ++mt){
        #pragma unroll
        for (int r = 0; r < 4; ++r){
            int trow = th * 32 + mt * 16 + lk * 4 + r;
            int idx  = tile * BM + trow;
            if (idx < ne){
                int pair = lrow[trow];
                float p  = pair_prob[pair];
                float* orow = dst + (size_t)(pair >> 1) * D_MODEL;
                #pragma unroll
                for (int nt = 0; nt < 8; ++nt){
                    int d = q * 128 + nt * 16 + l15;
                    atomicAdd(orow + d, p * yacc[mt][nt][r]);
                }
            }
        }
    }
}

// ---------------- fixed-order reduce of the split-1 partial ----------------
__global__ __launch_bounds__(256) void add_partial(float* __restrict__ out,
                                                   const float* __restrict__ part,
                                                   int n4){
    int i = blockIdx.x * blockDim.x + threadIdx.x;
    int stride = gridDim.x * blockDim.x;
    for (; i < n4; i += stride){
        float4 a = ((const float4*)out)[i];
        float4 b = ((const float4*)part)[i];
        a.x += b.x; a.y += b.y; a.z += b.z; a.w += b.w;
        ((float4*)out)[i] = a;
    }
}

extern "C" void kernel_launch(void* const* d_in, const int* in_sizes, int n_in,
                              void* d_out, int out_size, void* d_ws, size_t ws_size,
                              hipStream_t stream){
    const float* x  = (const float*)d_in[0];
    const float* Wr = (const float*)d_in[1];
    const float* W1 = (const float*)d_in[2];
    const float* W2 = (const float*)d_in[3];
    float* out = (float*)d_out;

    char* ws = (char*)d_ws;
    unsigned short* x_bf  = (unsigned short*)(ws);                 //  8,388,608 B
    unsigned short* W1bf  = (unsigned short*)(ws + 8388608);       // 16,777,216 B
    unsigned short* W2bf  = (unsigned short*)(ws + 25165824);      // 16,777,216 B
    float* pair_prob      = (float*)(ws + 41943040);               //     65,536 B
    int*   lists          = (int*)(ws + 42008576);                 //    262,144 B
    int*   cnt            = (int*)(ws + 42270720);                 //         32 B
    const size_t OFF_PART = 42271744;                              // 1KB-aligned
    const size_t NEED     = OFF_PART + (size_t)T_TOK * D_MODEL * 4;
    bool use_partial = ws_size >= NEED;
    float* partial = use_partial ? (float*)(ws + OFF_PART) : out;

    hipMemsetAsync(cnt, 0, NE * sizeof(int), stream);
    hipMemsetAsync(d_out, 0, (size_t)out_size * sizeof(float), stream);
    if (use_partial)
        hipMemsetAsync(partial, 0, (size_t)T_TOK * D_MODEL * 4, stream);

    cvt_f32_bf16<<<2048, 256, 0, stream>>>(W1, W1bf, (NE * D_FF * D_MODEL) / 4);
    cvt_f32_bf16<<<2048, 256, 0, stream>>>(W2, W2bf, (NE * D_MODEL * D_FF) / 4);

    router_kernel<<<(T_TOK * 64) / 256, 256, 0, stream>>>(x, Wr, x_bf, pair_prob, lists, cnt);

    // grid = 8 xcd-lanes x 256 slots (worst-case tiles); inactive blocks exit early
    moe_ffn_kernel<<<2048, 512, 0, stream>>>(x_bf, W1bf, W2bf, pair_prob, lists, cnt, out, partial);

    if (use_partial)
        add_partial<<<2048, 256, 0, stream>>>(out, partial, (T_TOK * D_MODEL) / 4);
}